// Round 6
// baseline (315.682 us; speedup 1.0000x reference)
//
#include <hip/hip_runtime.h>
#include <hip/hip_bf16.h>

#define NTOT 9216

using short8 = __attribute__((ext_vector_type(8))) short;
using f32x16 = __attribute__((ext_vector_type(16))) float;

__device__ __forceinline__ unsigned short bf16u(float f) {
  __hip_bfloat16 h = __float2bfloat16(f);
  return *reinterpret_cast<unsigned short*>(&h);
}
__device__ __forceinline__ float4 shfl_xor4(float4 v, int m) {
  float4 r;
  r.x = __shfl_xor(v.x, m); r.y = __shfl_xor(v.y, m);
  r.z = __shfl_xor(v.z, m); r.w = __shfl_xor(v.w, m);
  return r;
}

// LDS tile: [256 ch rows][64 n cols] bf16, row stride 144 B (16B pad: row shift
// = 36 banks -> 32 consecutive rows spread across banks, <=4-way on MFMA reads)
#define TB(buf, r, byte) ((buf) * 36992 + (r) * 144 + (byte))

// Fused LN + partial Gram. 16 blocks per batch, 9 chunks of 64 cols each.
// Stats/normalize straight from registers; 2 syncs per chunk; xbar in regs.
__global__ __launch_bounds__(1024) void kG(
    const float* __restrict__ x, const float* __restrict__ ln_w,
    const float* __restrict__ ln_b, float* __restrict__ Spart,
    float* __restrict__ xbarp) {
  __shared__ char tile[2 * 36992];
  __shared__ float4 sred1[256], sred2[256];   // [wave][colq]
  __shared__ float lw_s[256], lb_s[256];

  const int t = threadIdx.x, lane = t & 63, w = t >> 6;
  const int colq = t & 15, rowg = t >> 4;           // 4 cols, channels rowg+64j
  const int l31 = lane & 31, hi = lane >> 5;
  const int wr = w >> 2, wc = w & 3;
  const int b = blockIdx.x >> 4, p = blockIdx.x & 15;
  const float* xb = x + (size_t)b * 256 * NTOT;

  if (t < 256) { lw_s[t] = ln_w[t]; lb_s[t] = ln_b[t]; }

  f32x16 acc[2][2];
#pragma unroll
  for (int m = 0; m < 2; ++m)
#pragma unroll
    for (int n = 0; n < 2; ++n)
#pragma unroll
      for (int r = 0; r < 16; ++r) acc[m][n][r] = 0.f;
  float xacc[4] = {0.f, 0.f, 0.f, 0.f};

  int n0 = p * 9 * 64;
  float4 vreg[4];
#pragma unroll
  for (int j = 0; j < 4; ++j)
    vreg[j] = *reinterpret_cast<const float4*>(xb + (size_t)(rowg + 64 * j) * NTOT + n0 + colq * 4);

  for (int i = 0; i < 9; ++i) {
    const int buf = i & 1;
    // ---- stats from registers (shfl-only within wave: 16 channels/wave) ----
    float4 s1 = {0.f, 0.f, 0.f, 0.f}, s2 = {0.f, 0.f, 0.f, 0.f};
#pragma unroll
    for (int j = 0; j < 4; ++j) {
      const float4 v = vreg[j];
      s1.x += v.x; s1.y += v.y; s1.z += v.z; s1.w += v.w;
      s2.x += v.x * v.x; s2.y += v.y * v.y; s2.z += v.z * v.z; s2.w += v.w * v.w;
    }
    s1 += shfl_xor4(s1, 16); s1 += shfl_xor4(s1, 32);
    s2 += shfl_xor4(s2, 16); s2 += shfl_xor4(s2, 32);
    if (lane < 16) { sred1[w * 16 + lane] = s1; sred2[w * 16 + lane] = s2; }
    __syncthreads();                                   // S_a
    // ---- every thread reduces the 16 wave-partials for its own 4 columns ----
    {
      float4 a1 = {0.f, 0.f, 0.f, 0.f}, a2 = {0.f, 0.f, 0.f, 0.f};
#pragma unroll
      for (int ww = 0; ww < 16; ++ww) {
        float4 u1 = sred1[ww * 16 + colq], u2 = sred2[ww * 16 + colq];
        a1.x += u1.x; a1.y += u1.y; a1.z += u1.z; a1.w += u1.w;
        a2.x += u2.x; a2.y += u2.y; a2.z += u2.z; a2.w += u2.w;
      }
      const float inv = 1.f / 256.f;
      float4 mu, rc;
      mu.x = a1.x * inv; mu.y = a1.y * inv; mu.z = a1.z * inv; mu.w = a1.w * inv;
      rc.x = rsqrtf(a2.x * inv - mu.x * mu.x + 1e-5f);
      rc.y = rsqrtf(a2.y * inv - mu.y * mu.y + 1e-5f);
      rc.z = rsqrtf(a2.z * inv - mu.z * mu.z + 1e-5f);
      rc.w = rsqrtf(a2.w * inv - mu.w * mu.w + 1e-5f);
      // ---- normalize from fp32 regs, store bf16 tile, accumulate xbar ----
#pragma unroll
      for (int j = 0; j < 4; ++j) {
        const int r = rowg + 64 * j;
        const float g = lw_s[r], bb = lb_s[r];
        float f0 = (vreg[j].x - mu.x) * rc.x * g + bb;
        float f1 = (vreg[j].y - mu.y) * rc.y * g + bb;
        float f2 = (vreg[j].z - mu.z) * rc.z * g + bb;
        float f3 = (vreg[j].w - mu.w) * rc.w * g + bb;
        ushort4 o;
        o.x = bf16u(f0); o.y = bf16u(f1); o.z = bf16u(f2); o.w = bf16u(f3);
        *reinterpret_cast<ushort4*>(tile + TB(buf, r, colq * 8)) = o;
        xacc[j] += f0 + f1 + f2 + f3;
      }
    }
    // ---- prefetch next chunk (flies under barrier + MFMA) ----
    if (i < 8) {
      const int n1 = n0 + 64;
#pragma unroll
      for (int j = 0; j < 4; ++j)
        vreg[j] = *reinterpret_cast<const float4*>(xb + (size_t)(rowg + 64 * j) * NTOT + n1 + colq * 4);
    }
    __syncthreads();                                   // S_b
    // ---- partial Gram: 16 waves x 64x64, mfma 32x32x16 ----
#pragma unroll
    for (int kk = 0; kk < 4; ++kk) {
      short8 a0 = *reinterpret_cast<short8*>(tile + TB(buf, wr * 64 + l31,      kk * 32 + hi * 16));
      short8 a1 = *reinterpret_cast<short8*>(tile + TB(buf, wr * 64 + 32 + l31, kk * 32 + hi * 16));
      short8 b0 = *reinterpret_cast<short8*>(tile + TB(buf, wc * 64 + l31,      kk * 32 + hi * 16));
      short8 b1 = *reinterpret_cast<short8*>(tile + TB(buf, wc * 64 + 32 + l31, kk * 32 + hi * 16));
      acc[0][0] = __builtin_amdgcn_mfma_f32_32x32x16_bf16(a0, b0, acc[0][0], 0, 0, 0);
      acc[0][1] = __builtin_amdgcn_mfma_f32_32x32x16_bf16(a0, b1, acc[0][1], 0, 0, 0);
      acc[1][0] = __builtin_amdgcn_mfma_f32_32x32x16_bf16(a1, b0, acc[1][0], 0, 0, 0);
      acc[1][1] = __builtin_amdgcn_mfma_f32_32x32x16_bf16(a1, b1, acc[1][1], 0, 0, 0);
    }
    n0 += 64;
  }

  // ---- flush Gram partial (plain stores) ----
  float* Sp = Spart + (size_t)blockIdx.x * 65536;
#pragma unroll
  for (int m = 0; m < 2; ++m)
#pragma unroll
    for (int n = 0; n < 2; ++n)
#pragma unroll
      for (int r = 0; r < 16; ++r) {
        const int row = wr * 64 + m * 32 + (r & 3) + 8 * (r >> 2) + 4 * hi;
        const int col = wc * 64 + n * 32 + l31;
        Sp[row * 256 + col] = acc[m][n][r];
      }
  // ---- xbar: single end-of-kernel reduce across the 16 colq lanes ----
#pragma unroll
  for (int j = 0; j < 4; ++j) {
    float s = xacc[j];
    s += __shfl_xor(s, 1); s += __shfl_xor(s, 2);
    s += __shfl_xor(s, 4); s += __shfl_xor(s, 8);
    if ((lane & 15) == 0) xbarp[blockIdx.x * 256 + 64 * j + rowg] = s;
  }
}

// Reduce 16 partials per batch -> S[b]
__global__ __launch_bounds__(256) void kR(const float4* __restrict__ Spart,
                                          float4* __restrict__ S) {
  const int idx = blockIdx.x * 256 + threadIdx.x;
  const int b = idx >> 14, o = idx & 16383;
  float4 a = {0.f, 0.f, 0.f, 0.f};
#pragma unroll
  for (int p = 0; p < 16; ++p) {
    float4 v = Spart[(size_t)(b * 16 + p) * 16384 + o];
    a.x += v.x; a.y += v.y; a.z += v.z; a.w += v.w;
  }
  S[(size_t)b * 16384 + o] = a;
}

// Per (b,h): T = Wq_h.S ; logits = scale*T.Wk_h^T ; softmax ; vbar ; xabar
__global__ __launch_bounds__(256) void kC2(const float* __restrict__ S,
    const float* __restrict__ w_qkv, const float* __restrict__ xbarp,
    float* __restrict__ xabar) {
  __shared__ float wq_s[32 * 257];
  __shared__ float wk_s[32 * 257];
  __shared__ float att[32 * 33];
  __shared__ float xnb[256], vbp[256], vbar[32];
  const int t = threadIdx.x;
  const int b = blockIdx.x >> 3, h = blockIdx.x & 7;
  const float* Wq = w_qkv + (size_t)(h * 32) * 256;
  const float* Wk = w_qkv + (size_t)(256 + h * 32) * 256;
  const float* Wv = w_qkv + (size_t)(512 + h * 32) * 256;
  for (int i = t; i < 8192; i += 256) {
    const int r = i >> 8, c = i & 255;
    wq_s[r * 257 + c] = Wq[i];
    wk_s[r * 257 + c] = Wk[i];
  }
  {
    float s = 0.f;
#pragma unroll
    for (int p = 0; p < 16; ++p) s += xbarp[(b * 16 + p) * 256 + t];
    xnb[t] = s * (1.f / (float)NTOT);
  }
  __syncthreads();
  {
    const int e = t & 31, seg = t >> 5;
    float s = 0.f;
#pragma unroll
    for (int cc = 0; cc < 32; ++cc)
      s += Wv[e * 256 + seg * 32 + cc] * xnb[seg * 32 + cc];
    vbp[seg * 32 + e] = s;
  }
  __syncthreads();
  if (t < 32) {
    float s = 0.f;
#pragma unroll
    for (int seg = 0; seg < 8; ++seg) s += vbp[seg * 32 + t];
    vbar[t] = s;
  }
  float acc[32];
#pragma unroll
  for (int d = 0; d < 32; ++d) acc[d] = 0.f;
  const float* Sb = S + (size_t)b * 65536;
  for (int c = 0; c < 256; ++c) {
    const float sv = Sb[c * 256 + t];
#pragma unroll
    for (int d = 0; d < 32; ++d) acc[d] += wq_s[d * 257 + c] * sv;
  }
  __syncthreads();
#pragma unroll
  for (int d = 0; d < 32; ++d) wq_s[d * 257 + t] = acc[d];
  __syncthreads();
  {
    const int d = t >> 3, e0 = (t & 7) * 4;
    float l0 = 0.f, l1 = 0.f, l2 = 0.f, l3 = 0.f;
    for (int c = 0; c < 256; ++c) {
      const float tv = wq_s[d * 257 + c];
      l0 += tv * wk_s[(e0 + 0) * 257 + c];
      l1 += tv * wk_s[(e0 + 1) * 257 + c];
      l2 += tv * wk_s[(e0 + 2) * 257 + c];
      l3 += tv * wk_s[(e0 + 3) * 257 + c];
    }
    const float scale = 0.17677669529663687f;
    att[d * 33 + e0 + 0] = l0 * scale;
    att[d * 33 + e0 + 1] = l1 * scale;
    att[d * 33 + e0 + 2] = l2 * scale;
    att[d * 33 + e0 + 3] = l3 * scale;
  }
  __syncthreads();
  if (t < 32) {
    float mx = -1e30f;
#pragma unroll
    for (int e = 0; e < 32; ++e) mx = fmaxf(mx, att[t * 33 + e]);
    float sm = 0.f, xa = 0.f;
#pragma unroll
    for (int e = 0; e < 32; ++e) {
      float pe = expf(att[t * 33 + e] - mx);
      sm += pe; xa += pe * vbar[e];
    }
    xabar[b * 256 + h * 32 + t] = xa / sm;
  }
}

__global__ __launch_bounds__(256) void kD_out(const float* __restrict__ xabar,
    const float* __restrict__ w_proj, const float* __restrict__ b_proj,
    float* __restrict__ out) {
  __shared__ float xa[256];
  const int t = threadIdx.x, b = blockIdx.x;
  xa[t] = xabar[b * 256 + t];
  __syncthreads();
  float acc = b_proj[t];
  const float4* wp = reinterpret_cast<const float4*>(w_proj + (size_t)t * 256);
  const float4* xav = reinterpret_cast<const float4*>(xa);
#pragma unroll 4
  for (int c = 0; c < 64; ++c) {
    float4 wv = wp[c], xv = xav[c];
    acc += wv.x * xv.x + wv.y * xv.y + wv.z * xv.z + wv.w * xv.w;
  }
  out[b * 256 + t] = 1.f / (1.f + expf(-acc));
}

extern "C" void kernel_launch(void* const* d_in, const int* in_sizes, int n_in,
                              void* d_out, int out_size, void* d_ws, size_t ws_size,
                              hipStream_t stream) {
  const float* x      = (const float*)d_in[0];
  const float* ln_w   = (const float*)d_in[1];
  const float* ln_b   = (const float*)d_in[2];
  const float* w_qkv  = (const float*)d_in[3];
  const float* w_proj = (const float*)d_in[4];
  const float* b_proj = (const float*)d_in[5];
  float* out = (float*)d_out;

  char* ws = (char*)d_ws;
  float* Spart = (float*)ws;                       // 256*65536*4 = 67,108,864 B
  float* xbarp = (float*)(ws + 67108864);          // 256*256*4   =    262,144 B
  float* S     = (float*)(ws + 67371008);          // 16*65536*4  =  4,194,304 B
  float* xabar = (float*)(ws + 71565312);          // 16*256*4    =     16,384 B

  kG<<<256, 1024, 0, stream>>>(x, ln_w, ln_b, Spart, xbarp);
  kR<<<1024, 256, 0, stream>>>((const float4*)Spart, (float4*)S);
  kC2<<<128, 256, 0, stream>>>(S, w_qkv, xbarp, xabar);
  kD_out<<<16, 256, 0, stream>>>(xabar, w_proj, b_proj, out);
}